// Round 5
// baseline (885.899 us; speedup 1.0000x reference)
//
#include <hip/hip_runtime.h>

#define H 128
#define AP 136           // LDS row pitch in shorts
#define SCAN_BLK 1024

typedef __attribute__((ext_vector_type(8))) short short8;
typedef __attribute__((ext_vector_type(4))) float floatx4;

__device__ inline unsigned short f2b(float f) {   // fp32 -> bf16 RNE
  union { float f; unsigned u; } v; v.f = f;
  unsigned r = v.u + 0x7fffu + ((v.u >> 16) & 1u);
  return (unsigned short)(r >> 16);
}
__device__ inline float blo(unsigned u) { return __uint_as_float(u << 16); }
__device__ inline float bhi(unsigned u) { return __uint_as_float(u & 0xffff0000u); }

// ---------------- degree histogram + edge rank ----------------
__global__ __launch_bounds__(256) void k_deg(const int* __restrict__ dst,
                                             int* __restrict__ cnt,
                                             int* __restrict__ rank, int E) {
  int e = blockIdx.x * 256 + threadIdx.x;
  if (e < E) rank[e] = atomicAdd(&cnt[dst[e]], 1);
}

// ---------------- hierarchical scan ----------------
__global__ __launch_bounds__(256) void k_scan1(const int* __restrict__ cnt,
                                               int* __restrict__ bsum, int n) {
  __shared__ int red[256];
  int tid = threadIdx.x;
  int i0 = blockIdx.x * SCAN_BLK + tid * 4;
  int s = 0;
#pragma unroll
  for (int j = 0; j < 4; j++) { int i = i0 + j; if (i < n) s += cnt[i]; }
  red[tid] = s;
  __syncthreads();
  for (int off = 128; off > 0; off >>= 1) {
    if (tid < off) red[tid] += red[tid + off];
    __syncthreads();
  }
  if (tid == 0) bsum[blockIdx.x] = red[0];
}

__global__ __launch_bounds__(1024) void k_scan2(const int* __restrict__ bsum,
                                                int* __restrict__ boff,
                                                int* __restrict__ roff,
                                                int nb, int n) {
  __shared__ int sums[1024];
  int tid = threadIdx.x;
  int v = (tid < nb) ? bsum[tid] : 0;
  sums[tid] = v;
  __syncthreads();
  for (int off = 1; off < 1024; off <<= 1) {
    int t = (tid >= off) ? sums[tid - off] : 0;
    __syncthreads();
    sums[tid] += t;
    __syncthreads();
  }
  if (tid < nb) boff[tid] = sums[tid] - v;
  if (tid == 1023) roff[n] = sums[1023];
}

__global__ __launch_bounds__(256) void k_scan3(const int* __restrict__ cnt,
                                               const int* __restrict__ boff,
                                               int* __restrict__ roff,
                                               float* __restrict__ dinv, int n) {
  __shared__ int sums[256];
  int tid = threadIdx.x;
  int i0 = blockIdx.x * SCAN_BLK + tid * 4;
  int local[4];
  int s = 0;
#pragma unroll
  for (int j = 0; j < 4; j++) {
    int i = i0 + j;
    int v = (i < n) ? cnt[i] : 0;
    local[j] = s;
    s += v;
    if (i < n) dinv[i] = rsqrtf((float)v + 1.0f);
  }
  sums[tid] = s;
  __syncthreads();
  for (int off = 1; off < 256; off <<= 1) {
    int t = (tid >= off) ? sums[tid - off] : 0;
    __syncthreads();
    sums[tid] += t;
    __syncthreads();
  }
  int base = boff[blockIdx.x] + sums[tid] - s;
#pragma unroll
  for (int j = 0; j < 4; j++) {
    int i = i0 + j;
    if (i < n) roff[i] = base + local[j];
  }
}

// ---------------- CSR fill (atomic-free) ----------------
__global__ __launch_bounds__(256) void k_fill(const int* __restrict__ src,
                                              const int* __restrict__ dst,
                                              const int* __restrict__ rank,
                                              const int* __restrict__ roff,
                                              int* __restrict__ csr, int E) {
  int e = blockIdx.x * 256 + threadIdx.x;
  if (e < E) {
    int pos = roff[dst[e]] + rank[e];
    csr[pos] = src[e];
  }
}

// ---------------- W prep: fp32 [k][n] -> bf16 transposed [n][k] ----------------
__global__ __launch_bounds__(256) void k_prep_w(const float* __restrict__ W1,
                                                const float* __restrict__ W2,
                                                unsigned short* __restrict__ Wt1,
                                                unsigned short* __restrict__ Wt2) {
  const float* W = blockIdx.x ? W2 : W1;
  unsigned short* Wt = blockIdx.x ? Wt2 : Wt1;
  int tid = threadIdx.x;
#pragma unroll
  for (int i = 0; i < 64; i++) {
    int idx = tid + 256 * i;
    int k = idx >> 7, n = idx & 127;
    Wt[n * 128 + k] = f2b(W[idx]);
  }
}

// ---------------- x -> bf16 packed words ----------------
__global__ __launch_bounds__(256) void k_prep_xb(const float* __restrict__ x,
                                                 unsigned int* __restrict__ xb, int total) {
  int i = blockIdx.x * 256 + threadIdx.x;
  if (i < total) {
    float2 v = ((const float2*)x)[i];
    xb[i] = (unsigned)f2b(v.x) | ((unsigned)f2b(v.y) << 16);
  }
}

// ---------------- fused layer: y = (A_hat f) W + b + x ; relu -> bf16 or fp32 out ----
// block = 64 nodes; wave w aggregates nodes [row0+w*16, +16) into LDS A-tile,
// then MFMA with W (staged in LDS), epilogue adds bias + bf16 x residual.
__global__ __launch_bounds__(256) void k_fused(const unsigned int* __restrict__ fin, // bf16x2 words [n][64]
                                               const unsigned short* __restrict__ Wt, // [n][k] bf16
                                               const float* __restrict__ bias,
                                               const unsigned short* __restrict__ xb, // bf16 [n][128]
                                               const int* __restrict__ csr,
                                               const int* __restrict__ roff,
                                               const float* __restrict__ dinv,
                                               unsigned short* __restrict__ out16,
                                               float* __restrict__ out32,
                                               int n, int write16) {
  __shared__ short As[64 * AP];    // aggregated tile, bf16
  __shared__ short Bs[128 * AP];   // W^T tile, bf16
  int tid = threadIdx.x;
  int wave = tid >> 6, lane = tid & 63;
  int quad = lane >> 4, l16 = lane & 15;
  int row0 = blockIdx.x * 64;

  // stage B (independent of agg phase)
  const float4* Wt4 = (const float4*)Wt;
#pragma unroll
  for (int i = 0; i < 8; i++) {
    int idx = tid + 256 * i;
    int nr = idx >> 4, c = idx & 15;
    *(float4*)&Bs[nr * AP + c * 8] = Wt4[nr * 16 + c];
  }

  // aggregation phase: one wave per 16 nodes, results -> As
  for (int j = 0; j < 16; j++) {
    int node = row0 + wave * 16 + j;
    float acc0 = 0.f, acc1 = 0.f;
    if (node < n) {
      float di = dinv[node];
      unsigned su = fin[node * 64 + lane];
      acc0 = di * di * blo(su);
      acc1 = di * di * bhi(su);
      int e0 = roff[node], e1 = roff[node + 1];
      int e = e0;
      for (; e + 4 <= e1; e += 4) {
        int i0 = csr[e], i1 = csr[e + 1], i2 = csr[e + 2], i3 = csr[e + 3];
        float c0 = di * dinv[i0], c1 = di * dinv[i1];
        float c2 = di * dinv[i2], c3 = di * dinv[i3];
        unsigned u0 = fin[i0 * 64 + lane];
        unsigned u1 = fin[i1 * 64 + lane];
        unsigned u2 = fin[i2 * 64 + lane];
        unsigned u3 = fin[i3 * 64 + lane];
        acc0 += c0 * blo(u0) + c1 * blo(u1);
        acc1 += c0 * bhi(u0) + c1 * bhi(u1);
        acc0 += c2 * blo(u2) + c3 * blo(u3);
        acc1 += c2 * bhi(u2) + c3 * bhi(u3);
      }
      for (; e < e1; e++) {
        int s = csr[e];
        float cf = di * dinv[s];
        unsigned u = fin[s * 64 + lane];
        acc0 += cf * blo(u);
        acc1 += cf * bhi(u);
      }
    }
    unsigned w = (unsigned)f2b(acc0) | ((unsigned)f2b(acc1) << 16);
    *(unsigned*)&As[(wave * 16 + j) * AP + lane * 2] = w;
  }
  __syncthreads();

  // MFMA phase: wave covers cols [wave*32, +32), all 64 rows
  floatx4 acc[4][2];
#pragma unroll
  for (int mt = 0; mt < 4; mt++)
#pragma unroll
    for (int nt = 0; nt < 2; nt++) acc[mt][nt] = (floatx4)(0.f);

#pragma unroll
  for (int ks = 0; ks < 4; ks++) {
    short8 a[4], b[2];
#pragma unroll
    for (int mt = 0; mt < 4; mt++)
      a[mt] = *(const short8*)&As[(mt * 16 + l16) * AP + ks * 32 + quad * 8];
#pragma unroll
    for (int nt = 0; nt < 2; nt++)
      b[nt] = *(const short8*)&Bs[(wave * 32 + nt * 16 + l16) * AP + ks * 32 + quad * 8];
#pragma unroll
    for (int mt = 0; mt < 4; mt++)
#pragma unroll
      for (int nt = 0; nt < 2; nt++)
        acc[mt][nt] = __builtin_amdgcn_mfma_f32_16x16x32_bf16(a[mt], b[nt], acc[mt][nt], 0, 0, 0);
  }

  // epilogue: C/D layout col=l16 (+nt*16+wave*32), row=quad*4+r (+mt*16)
#pragma unroll
  for (int nt = 0; nt < 2; nt++) {
    int col = wave * 32 + nt * 16 + l16;
    float bcol = bias[col];
#pragma unroll
    for (int mt = 0; mt < 4; mt++) {
#pragma unroll
      for (int r = 0; r < 4; r++) {
        int gr = row0 + mt * 16 + quad * 4 + r;
        if (gr < n) {
          float xv = __uint_as_float(((unsigned)xb[gr * H + col]) << 16);
          float y = acc[mt][nt][r] + bcol + xv;
          if (write16) out16[(size_t)gr * H + col] = f2b(fmaxf(y, 0.f));
          else out32[(size_t)gr * H + col] = y;
        }
      }
    }
  }
}

extern "C" void kernel_launch(void* const* d_in, const int* in_sizes, int n_in,
                              void* d_out, int out_size, void* d_ws, size_t ws_size,
                              hipStream_t stream) {
  const float* x = (const float*)d_in[0];
  const int* src = (const int*)d_in[1];
  const int* dst = (const int*)d_in[2];
  const float* W1 = (const float*)d_in[3];
  const float* b1 = (const float*)d_in[4];
  const float* W2 = (const float*)d_in[5];
  const float* b2 = (const float*)d_in[6];
  int N = in_sizes[0] / H;
  int E = in_sizes[1];
  float* out = (float*)d_out;

  char* p = (char*)d_ws;
  auto alloc = [&](size_t bytes) {
    char* q = p;
    p += (bytes + 255) & ~(size_t)255;
    return q;
  };
  int* cnt = (int*)alloc((size_t)N * 4);
  int* roff = (int*)alloc((size_t)(N + 1) * 4);
  float* dinv = (float*)alloc((size_t)N * 4);
  int* rank = (int*)alloc((size_t)E * 4);
  int* csr = (int*)alloc((size_t)E * 4);
  unsigned int* xb = (unsigned int*)alloc((size_t)N * H * 2);     // bf16 x
  unsigned int* fA = (unsigned int*)alloc((size_t)N * H * 2);     // bf16 features ping
  unsigned int* fB = (unsigned int*)alloc((size_t)N * H * 2);     // bf16 features pong
  unsigned short* Wt1 = (unsigned short*)alloc(128 * 128 * 2);
  unsigned short* Wt2 = (unsigned short*)alloc(128 * 128 * 2);
  int* bsum = (int*)alloc(1024 * 4);
  int* boff = (int*)alloc(1024 * 4);

  int nb = (N + SCAN_BLK - 1) / SCAN_BLK;  // 98 for N=100000

  hipMemsetAsync(cnt, 0, (size_t)N * 4, stream);
  k_deg<<<(E + 255) / 256, 256, 0, stream>>>(dst, cnt, rank, E);
  k_scan1<<<nb, 256, 0, stream>>>(cnt, bsum, N);
  k_scan2<<<1, 1024, 0, stream>>>(bsum, boff, roff, nb, N);
  k_scan3<<<nb, 256, 0, stream>>>(cnt, boff, roff, dinv, N);
  k_fill<<<(E + 255) / 256, 256, 0, stream>>>(src, dst, rank, roff, csr, E);
  k_prep_w<<<2, 256, 0, stream>>>(W1, W2, Wt1, Wt2);
  k_prep_xb<<<(N * (H / 2) + 255) / 256, 256, 0, stream>>>(x, xb, N * (H / 2));

  int gb = (N + 63) / 64;

  // layer 1: f = xb, W1/b1, relu -> bf16 fA
  k_fused<<<gb, 256, 0, stream>>>(xb, Wt1, b1, (const unsigned short*)xb, csr, roff, dinv,
                                  (unsigned short*)fA, nullptr, N, 1);
  // layer 2: f = fA, W2/b2, relu -> bf16 fB
  k_fused<<<gb, 256, 0, stream>>>(fA, Wt2, b2, (const unsigned short*)xb, csr, roff, dinv,
                                  (unsigned short*)fB, nullptr, N, 1);
  // layer 3: f = fB, W2/b2, no relu -> fp32 out
  k_fused<<<gb, 256, 0, stream>>>(fB, Wt2, b2, (const unsigned short*)xb, csr, roff, dinv,
                                  nullptr, out, N, 0);
}

// Round 6
// 516.344 us; speedup vs baseline: 1.7157x; 1.7157x over previous
//
#include <hip/hip_runtime.h>

#define H 128
#define AP 136           // LDS row pitch in shorts
#define SCAN_BLK 1024

typedef __attribute__((ext_vector_type(8))) short short8;
typedef __attribute__((ext_vector_type(4))) float floatx4;

__device__ inline unsigned short f2b(float f) {   // fp32 -> bf16 RNE
  union { float f; unsigned u; } v; v.f = f;
  unsigned r = v.u + 0x7fffu + ((v.u >> 16) & 1u);
  return (unsigned short)(r >> 16);
}
__device__ inline float blo(unsigned u) { return __uint_as_float(u << 16); }
__device__ inline float bhi(unsigned u) { return __uint_as_float(u & 0xffff0000u); }

// ---------------- degree histogram + edge rank ----------------
__global__ __launch_bounds__(256) void k_deg(const int* __restrict__ dst,
                                             int* __restrict__ cnt,
                                             int* __restrict__ rank, int E) {
  int e = blockIdx.x * 256 + threadIdx.x;
  if (e < E) rank[e] = atomicAdd(&cnt[dst[e]], 1);
}

// ---------------- hierarchical scan ----------------
__global__ __launch_bounds__(256) void k_scan1(const int* __restrict__ cnt,
                                               int* __restrict__ bsum, int n) {
  __shared__ int red[256];
  int tid = threadIdx.x;
  int i0 = blockIdx.x * SCAN_BLK + tid * 4;
  int s = 0;
#pragma unroll
  for (int j = 0; j < 4; j++) { int i = i0 + j; if (i < n) s += cnt[i]; }
  red[tid] = s;
  __syncthreads();
  for (int off = 128; off > 0; off >>= 1) {
    if (tid < off) red[tid] += red[tid + off];
    __syncthreads();
  }
  if (tid == 0) bsum[blockIdx.x] = red[0];
}

__global__ __launch_bounds__(1024) void k_scan2(const int* __restrict__ bsum,
                                                int* __restrict__ boff,
                                                int* __restrict__ roff,
                                                int nb, int n) {
  __shared__ int sums[1024];
  int tid = threadIdx.x;
  int v = (tid < nb) ? bsum[tid] : 0;
  sums[tid] = v;
  __syncthreads();
  for (int off = 1; off < 1024; off <<= 1) {
    int t = (tid >= off) ? sums[tid - off] : 0;
    __syncthreads();
    sums[tid] += t;
    __syncthreads();
  }
  if (tid < nb) boff[tid] = sums[tid] - v;
  if (tid == 1023) roff[n] = sums[1023];
}

__global__ __launch_bounds__(256) void k_scan3(const int* __restrict__ cnt,
                                               const int* __restrict__ boff,
                                               int* __restrict__ roff,
                                               float* __restrict__ dinv, int n) {
  __shared__ int sums[256];
  int tid = threadIdx.x;
  int i0 = blockIdx.x * SCAN_BLK + tid * 4;
  int local[4];
  int s = 0;
#pragma unroll
  for (int j = 0; j < 4; j++) {
    int i = i0 + j;
    int v = (i < n) ? cnt[i] : 0;
    local[j] = s;
    s += v;
    if (i < n) dinv[i] = rsqrtf((float)v + 1.0f);
  }
  sums[tid] = s;
  __syncthreads();
  for (int off = 1; off < 256; off <<= 1) {
    int t = (tid >= off) ? sums[tid - off] : 0;
    __syncthreads();
    sums[tid] += t;
    __syncthreads();
  }
  int base = boff[blockIdx.x] + sums[tid] - s;
#pragma unroll
  for (int j = 0; j < 4; j++) {
    int i = i0 + j;
    if (i < n) roff[i] = base + local[j];
  }
}

// ---------------- CSR fill (atomic-free) ----------------
__global__ __launch_bounds__(256) void k_fill(const int* __restrict__ src,
                                              const int* __restrict__ dst,
                                              const int* __restrict__ rank,
                                              const int* __restrict__ roff,
                                              int* __restrict__ csr, int E) {
  int e = blockIdx.x * 256 + threadIdx.x;
  if (e < E) {
    int pos = roff[dst[e]] + rank[e];
    csr[pos] = src[e];
  }
}

// ---------------- W prep: fp32 [k][n] -> bf16 transposed [n][k] ----------------
__global__ __launch_bounds__(256) void k_prep_w(const float* __restrict__ W1,
                                                const float* __restrict__ W2,
                                                unsigned short* __restrict__ Wt1,
                                                unsigned short* __restrict__ Wt2) {
  const float* W = blockIdx.x ? W2 : W1;
  unsigned short* Wt = blockIdx.x ? Wt2 : Wt1;
  int tid = threadIdx.x;
#pragma unroll
  for (int i = 0; i < 64; i++) {
    int idx = tid + 256 * i;
    int k = idx >> 7, n = idx & 127;
    Wt[n * 128 + k] = f2b(W[idx]);
  }
}

// ---------------- x -> bf16 packed words ----------------
__global__ __launch_bounds__(256) void k_prep_xb(const float* __restrict__ x,
                                                 unsigned int* __restrict__ xb, int total) {
  int i = blockIdx.x * 256 + threadIdx.x;
  if (i < total) {
    float2 v = ((const float2*)x)[i];
    xb[i] = (unsigned)f2b(v.x) | ((unsigned)f2b(v.y) << 16);
  }
}

// ---------------- bf16 MFMA GEMM: out_bf16 = in_bf16 @ W ----------------
__global__ __launch_bounds__(256) void k_gemm(const unsigned int* __restrict__ in, // bf16x2 [n][64]
                                              const unsigned short* __restrict__ Wt, // [n][k] bf16
                                              unsigned short* __restrict__ out,      // [m][n] bf16
                                              int n) {
  __shared__ short As[64 * AP];
  __shared__ short Bs[128 * AP];
  int tid = threadIdx.x;
  int wave = tid >> 6, lane = tid & 63;
  int quad = lane >> 4, l16 = lane & 15;
  int row0 = blockIdx.x * 64;

  // stage A: 64 rows x 128 shorts = 1024 16B-chunks
  const float4* in4 = (const float4*)in;
#pragma unroll
  for (int i = 0; i < 4; i++) {
    int idx = tid + 256 * i;
    int r = idx >> 4, c = idx & 15;
    int gr = row0 + r;
    float4 v = make_float4(0.f, 0.f, 0.f, 0.f);
    if (gr < n) v = in4[(size_t)gr * 16 + c];
    *(float4*)&As[r * AP + c * 8] = v;
  }
  // stage B
  const float4* Wt4 = (const float4*)Wt;
#pragma unroll
  for (int i = 0; i < 8; i++) {
    int idx = tid + 256 * i;
    int nr = idx >> 4, c = idx & 15;
    *(float4*)&Bs[nr * AP + c * 8] = Wt4[nr * 16 + c];
  }
  __syncthreads();

  floatx4 acc[4][2];
#pragma unroll
  for (int mt = 0; mt < 4; mt++)
#pragma unroll
    for (int nt = 0; nt < 2; nt++) acc[mt][nt] = (floatx4)(0.f);

#pragma unroll
  for (int ks = 0; ks < 4; ks++) {
    short8 a[4], b[2];
#pragma unroll
    for (int mt = 0; mt < 4; mt++)
      a[mt] = *(const short8*)&As[(mt * 16 + l16) * AP + ks * 32 + quad * 8];
#pragma unroll
    for (int nt = 0; nt < 2; nt++)
      b[nt] = *(const short8*)&Bs[(wave * 32 + nt * 16 + l16) * AP + ks * 32 + quad * 8];
#pragma unroll
    for (int mt = 0; mt < 4; mt++)
#pragma unroll
      for (int nt = 0; nt < 2; nt++)
        acc[mt][nt] = __builtin_amdgcn_mfma_f32_16x16x32_bf16(a[mt], b[nt], acc[mt][nt], 0, 0, 0);
  }

#pragma unroll
  for (int mt = 0; mt < 4; mt++) {
#pragma unroll
    for (int nt = 0; nt < 2; nt++) {
#pragma unroll
      for (int r = 0; r < 4; r++) {
        int gr = row0 + mt * 16 + quad * 4 + r;
        if (gr < n)
          out[(size_t)gr * H + wave * 32 + nt * 16 + l16] = f2b(acc[mt][nt][r]);
      }
    }
  }
}

// ---------------- aggregation: one wave per node, 8x unrolled bf16 gathers ------
// y[i,:] = b + xb[i,:] + dinv[i]^2 * h[i,:] + sum_e dinv[src]*dinv[i]*h[src,:]
// write16=1: out16 = bf16(relu(y));  write16=0: out32 = y
__global__ __launch_bounds__(256) void k_agg(const unsigned int* __restrict__ h, // bf16x2 words
                                             const int* __restrict__ csr,
                                             const int* __restrict__ roff,
                                             const float* __restrict__ dinv,
                                             const float* __restrict__ bias,
                                             const unsigned int* __restrict__ xb,
                                             float* __restrict__ out32,
                                             unsigned int* __restrict__ out16,
                                             int n, int write16) {
  int wave = threadIdx.x >> 6;
  int lane = threadIdx.x & 63;
  int node = blockIdx.x * 4 + wave;
  if (node >= n) return;

  float di = dinv[node];
  unsigned su = h[(size_t)node * 64 + lane];
  unsigned xu = xb[(size_t)node * 64 + lane];
  float2 bv = ((const float2*)bias)[lane];
  float acc0 = bv.x + blo(xu) + di * di * blo(su);
  float acc1 = bv.y + bhi(xu) + di * di * bhi(su);

  int e0 = roff[node], e1 = roff[node + 1];
  int e = e0;
  for (; e + 8 <= e1; e += 8) {
    int idx[8];
#pragma unroll
    for (int k = 0; k < 8; k++) idx[k] = csr[e + k];
    float cf[8];
#pragma unroll
    for (int k = 0; k < 8; k++) cf[k] = di * dinv[idx[k]];
    unsigned u[8];
#pragma unroll
    for (int k = 0; k < 8; k++) u[k] = h[(size_t)idx[k] * 64 + lane];
#pragma unroll
    for (int k = 0; k < 8; k++) {
      acc0 += cf[k] * blo(u[k]);
      acc1 += cf[k] * bhi(u[k]);
    }
  }
  for (; e < e1; e++) {
    int s = csr[e];
    float cf = di * dinv[s];
    unsigned u = h[(size_t)s * 64 + lane];
    acc0 += cf * blo(u);
    acc1 += cf * bhi(u);
  }
  if (write16) {
    out16[(size_t)node * 64 + lane] =
        (unsigned)f2b(fmaxf(acc0, 0.f)) | ((unsigned)f2b(fmaxf(acc1, 0.f)) << 16);
  } else {
    ((float2*)out32)[(size_t)node * 64 + lane] = make_float2(acc0, acc1);
  }
}

extern "C" void kernel_launch(void* const* d_in, const int* in_sizes, int n_in,
                              void* d_out, int out_size, void* d_ws, size_t ws_size,
                              hipStream_t stream) {
  const float* x = (const float*)d_in[0];
  const int* src = (const int*)d_in[1];
  const int* dst = (const int*)d_in[2];
  const float* W1 = (const float*)d_in[3];
  const float* b1 = (const float*)d_in[4];
  const float* W2 = (const float*)d_in[5];
  const float* b2 = (const float*)d_in[6];
  int N = in_sizes[0] / H;
  int E = in_sizes[1];
  float* out = (float*)d_out;

  char* p = (char*)d_ws;
  auto alloc = [&](size_t bytes) {
    char* q = p;
    p += (bytes + 255) & ~(size_t)255;
    return q;
  };
  int* cnt = (int*)alloc((size_t)N * 4);
  int* roff = (int*)alloc((size_t)(N + 1) * 4);
  float* dinv = (float*)alloc((size_t)N * 4);
  int* csr = (int*)alloc((size_t)E * 4);
  unsigned int* xb = (unsigned int*)alloc((size_t)N * H * 2);         // bf16 x
  unsigned short* htmp = (unsigned short*)alloc((size_t)N * H * 2);   // bf16 h = f@W
  unsigned int* fbuf = (unsigned int*)alloc((size_t)N * H * 2);       // bf16 relu(y)
  unsigned short* Wt1 = (unsigned short*)alloc(128 * 128 * 2);
  unsigned short* Wt2 = (unsigned short*)alloc(128 * 128 * 2);
  int* bsum = (int*)alloc(1024 * 4);
  int* boff = (int*)alloc(1024 * 4);
  // rank aliases htmp: rank is only live deg->fill, htmp first written after fill
  int* rank = (int*)htmp;

  int nb = (N + SCAN_BLK - 1) / SCAN_BLK;  // 98 for N=100000

  hipMemsetAsync(cnt, 0, (size_t)N * 4, stream);
  k_deg<<<(E + 255) / 256, 256, 0, stream>>>(dst, cnt, rank, E);
  k_scan1<<<nb, 256, 0, stream>>>(cnt, bsum, N);
  k_scan2<<<1, 1024, 0, stream>>>(bsum, boff, roff, nb, N);
  k_scan3<<<nb, 256, 0, stream>>>(cnt, boff, roff, dinv, N);
  k_fill<<<(E + 255) / 256, 256, 0, stream>>>(src, dst, rank, roff, csr, E);
  k_prep_w<<<2, 256, 0, stream>>>(W1, W2, Wt1, Wt2);
  k_prep_xb<<<(N * (H / 2) + 255) / 256, 256, 0, stream>>>(x, xb, N * (H / 2));

  int gb = (N + 63) / 64;
  int ab = (N + 3) / 4;

  // layer 1: h = xb @ W1 ; y1 = agg(h) + b1 + xb ; relu -> fbuf
  k_gemm<<<gb, 256, 0, stream>>>(xb, Wt1, htmp, N);
  k_agg<<<ab, 256, 0, stream>>>((const unsigned int*)htmp, csr, roff, dinv, b1, xb,
                                nullptr, fbuf, N, 1);
  // layer 2
  k_gemm<<<gb, 256, 0, stream>>>(fbuf, Wt2, htmp, N);
  k_agg<<<ab, 256, 0, stream>>>((const unsigned int*)htmp, csr, roff, dinv, b2, xb,
                                nullptr, fbuf, N, 1);
  // layer 3 -> fp32 out
  k_gemm<<<gb, 256, 0, stream>>>(fbuf, Wt2, htmp, N);
  k_agg<<<ab, 256, 0, stream>>>((const unsigned int*)htmp, csr, roff, dinv, b2, xb,
                                out, nullptr, N, 0);
}

// Round 7
// 477.774 us; speedup vs baseline: 1.8542x; 1.0807x over previous
//
#include <hip/hip_runtime.h>

#define H 128
#define AP 136           // LDS row pitch in shorts
#define SCAN_BLK 1024

typedef __attribute__((ext_vector_type(8))) short short8;
typedef __attribute__((ext_vector_type(4))) float floatx4;

__device__ inline unsigned short f2b(float f) {   // fp32 -> bf16 RNE
  union { float f; unsigned u; } v; v.f = f;
  unsigned r = v.u + 0x7fffu + ((v.u >> 16) & 1u);
  return (unsigned short)(r >> 16);
}
__device__ inline float blo(unsigned u) { return __uint_as_float(u << 16); }
__device__ inline float bhi(unsigned u) { return __uint_as_float(u & 0xffff0000u); }
__device__ inline unsigned char f2f8(float f) {   // fp32 -> fp8 e4m3 (OCP, RNE)
  return (unsigned char)(__builtin_amdgcn_cvt_pk_fp8_f32(f, f, 0, false) & 0xff);
}

// ---------------- degree histogram + edge rank ----------------
__global__ __launch_bounds__(256) void k_deg(const int* __restrict__ dst,
                                             int* __restrict__ cnt,
                                             int* __restrict__ rank, int E) {
  int e = blockIdx.x * 256 + threadIdx.x;
  if (e < E) rank[e] = atomicAdd(&cnt[dst[e]], 1);
}

// ---------------- hierarchical scan ----------------
__global__ __launch_bounds__(256) void k_scan1(const int* __restrict__ cnt,
                                               int* __restrict__ bsum, int n) {
  __shared__ int red[256];
  int tid = threadIdx.x;
  int i0 = blockIdx.x * SCAN_BLK + tid * 4;
  int s = 0;
#pragma unroll
  for (int j = 0; j < 4; j++) { int i = i0 + j; if (i < n) s += cnt[i]; }
  red[tid] = s;
  __syncthreads();
  for (int off = 128; off > 0; off >>= 1) {
    if (tid < off) red[tid] += red[tid + off];
    __syncthreads();
  }
  if (tid == 0) bsum[blockIdx.x] = red[0];
}

__global__ __launch_bounds__(1024) void k_scan2(const int* __restrict__ bsum,
                                                int* __restrict__ boff,
                                                int* __restrict__ roff,
                                                int nb, int n) {
  __shared__ int sums[1024];
  int tid = threadIdx.x;
  int v = (tid < nb) ? bsum[tid] : 0;
  sums[tid] = v;
  __syncthreads();
  for (int off = 1; off < 1024; off <<= 1) {
    int t = (tid >= off) ? sums[tid - off] : 0;
    __syncthreads();
    sums[tid] += t;
    __syncthreads();
  }
  if (tid < nb) boff[tid] = sums[tid] - v;
  if (tid == 1023) roff[n] = sums[1023];
}

__global__ __launch_bounds__(256) void k_scan3(const int* __restrict__ cnt,
                                               const int* __restrict__ boff,
                                               int* __restrict__ roff,
                                               float* __restrict__ dinv, int n) {
  __shared__ int sums[256];
  int tid = threadIdx.x;
  int i0 = blockIdx.x * SCAN_BLK + tid * 4;
  int local[4];
  int s = 0;
#pragma unroll
  for (int j = 0; j < 4; j++) {
    int i = i0 + j;
    int v = (i < n) ? cnt[i] : 0;
    local[j] = s;
    s += v;
    if (i < n) dinv[i] = rsqrtf((float)v + 1.0f);
  }
  sums[tid] = s;
  __syncthreads();
  for (int off = 1; off < 256; off <<= 1) {
    int t = (tid >= off) ? sums[tid - off] : 0;
    __syncthreads();
    sums[tid] += t;
    __syncthreads();
  }
  int base = boff[blockIdx.x] + sums[tid] - s;
#pragma unroll
  for (int j = 0; j < 4; j++) {
    int i = i0 + j;
    if (i < n) roff[i] = base + local[j];
  }
}

// ---------------- CSR fill (atomic-free) ----------------
__global__ __launch_bounds__(256) void k_fill(const int* __restrict__ src,
                                              const int* __restrict__ dst,
                                              const int* __restrict__ rank,
                                              const int* __restrict__ roff,
                                              int* __restrict__ csr, int E) {
  int e = blockIdx.x * 256 + threadIdx.x;
  if (e < E) {
    int pos = roff[dst[e]] + rank[e];
    csr[pos] = src[e];
  }
}

// ---------------- W prep: fp32 [k][n] -> bf16 transposed [n][k] ----------------
__global__ __launch_bounds__(256) void k_prep_w(const float* __restrict__ W1,
                                                const float* __restrict__ W2,
                                                unsigned short* __restrict__ Wt1,
                                                unsigned short* __restrict__ Wt2) {
  const float* W = blockIdx.x ? W2 : W1;
  unsigned short* Wt = blockIdx.x ? Wt2 : Wt1;
  int tid = threadIdx.x;
#pragma unroll
  for (int i = 0; i < 64; i++) {
    int idx = tid + 256 * i;
    int k = idx >> 7, n = idx & 127;
    Wt[n * 128 + k] = f2b(W[idx]);
  }
}

// ---------------- x -> bf16 packed words ----------------
__global__ __launch_bounds__(256) void k_prep_xb(const float* __restrict__ x,
                                                 unsigned int* __restrict__ xb, int total) {
  int i = blockIdx.x * 256 + threadIdx.x;
  if (i < total) {
    float2 v = ((const float2*)x)[i];
    xb[i] = (unsigned)f2b(v.x) | ((unsigned)f2b(v.y) << 16);
  }
}

// ---------------- bf16 MFMA GEMM: out_fp8 = in_bf16 @ W ----------------
__global__ __launch_bounds__(256) void k_gemm(const unsigned int* __restrict__ in, // bf16x2 [n][64]
                                              const unsigned short* __restrict__ Wt, // [n][k] bf16
                                              unsigned char* __restrict__ out,       // [m][n] fp8
                                              int n) {
  __shared__ short As[64 * AP];
  __shared__ short Bs[128 * AP];
  int tid = threadIdx.x;
  int wave = tid >> 6, lane = tid & 63;
  int quad = lane >> 4, l16 = lane & 15;
  int row0 = blockIdx.x * 64;

  // stage A: 64 rows x 128 shorts = 1024 16B-chunks
  const float4* in4 = (const float4*)in;
#pragma unroll
  for (int i = 0; i < 4; i++) {
    int idx = tid + 256 * i;
    int r = idx >> 4, c = idx & 15;
    int gr = row0 + r;
    float4 v = make_float4(0.f, 0.f, 0.f, 0.f);
    if (gr < n) v = in4[(size_t)gr * 16 + c];
    *(float4*)&As[r * AP + c * 8] = v;
  }
  // stage B
  const float4* Wt4 = (const float4*)Wt;
#pragma unroll
  for (int i = 0; i < 8; i++) {
    int idx = tid + 256 * i;
    int nr = idx >> 4, c = idx & 15;
    *(float4*)&Bs[nr * AP + c * 8] = Wt4[nr * 16 + c];
  }
  __syncthreads();

  floatx4 acc[4][2];
#pragma unroll
  for (int mt = 0; mt < 4; mt++)
#pragma unroll
    for (int nt = 0; nt < 2; nt++) acc[mt][nt] = (floatx4)(0.f);

#pragma unroll
  for (int ks = 0; ks < 4; ks++) {
    short8 a[4], b[2];
#pragma unroll
    for (int mt = 0; mt < 4; mt++)
      a[mt] = *(const short8*)&As[(mt * 16 + l16) * AP + ks * 32 + quad * 8];
#pragma unroll
    for (int nt = 0; nt < 2; nt++)
      b[nt] = *(const short8*)&Bs[(wave * 32 + nt * 16 + l16) * AP + ks * 32 + quad * 8];
#pragma unroll
    for (int mt = 0; mt < 4; mt++)
#pragma unroll
      for (int nt = 0; nt < 2; nt++)
        acc[mt][nt] = __builtin_amdgcn_mfma_f32_16x16x32_bf16(a[mt], b[nt], acc[mt][nt], 0, 0, 0);
  }

#pragma unroll
  for (int mt = 0; mt < 4; mt++) {
#pragma unroll
    for (int nt = 0; nt < 2; nt++) {
#pragma unroll
      for (int r = 0; r < 4; r++) {
        int gr = row0 + mt * 16 + quad * 4 + r;
        if (gr < n)
          out[(size_t)gr * H + wave * 32 + nt * 16 + l16] = f2f8(acc[mt][nt][r]);
      }
    }
  }
}

// ---------------- aggregation: one wave per node, fp8 h gathers (128B rows) ----
// y[i,:] = b + xb[i,:] + dinv[i]^2 * h[i,:] + sum_e dinv[src]*dinv[i]*h[src,:]
// write16=1: out16 = bf16(relu(y));  write16=0: out32 = y
__global__ __launch_bounds__(256) void k_agg(const unsigned short* __restrict__ h, // fp8 pairs
                                             const int* __restrict__ csr,
                                             const int* __restrict__ roff,
                                             const float* __restrict__ dinv,
                                             const float* __restrict__ bias,
                                             const unsigned int* __restrict__ xb,
                                             float* __restrict__ out32,
                                             unsigned int* __restrict__ out16,
                                             int n, int write16) {
  int wave = threadIdx.x >> 6;
  int lane = threadIdx.x & 63;
  int node = blockIdx.x * 4 + wave;
  if (node >= n) return;

  float di = dinv[node];
  unsigned su = h[(size_t)node * 64 + lane];           // 2 fp8
  unsigned xu = xb[(size_t)node * 64 + lane];          // 2 bf16
  float2 bv = ((const float2*)bias)[lane];
  float acc0 = bv.x + blo(xu) + di * di * __builtin_amdgcn_cvt_f32_fp8(su, 0);
  float acc1 = bv.y + bhi(xu) + di * di * __builtin_amdgcn_cvt_f32_fp8(su, 1);

  int e0 = roff[node], e1 = roff[node + 1];
  int e = e0;
  for (; e + 8 <= e1; e += 8) {
    int idx[8];
#pragma unroll
    for (int k = 0; k < 8; k++) idx[k] = csr[e + k];
    float cf[8];
#pragma unroll
    for (int k = 0; k < 8; k++) cf[k] = di * dinv[idx[k]];
    unsigned u[8];
#pragma unroll
    for (int k = 0; k < 8; k++) u[k] = h[(size_t)idx[k] * 64 + lane];
#pragma unroll
    for (int k = 0; k < 8; k++) {
      acc0 += cf[k] * __builtin_amdgcn_cvt_f32_fp8(u[k], 0);
      acc1 += cf[k] * __builtin_amdgcn_cvt_f32_fp8(u[k], 1);
    }
  }
  for (; e < e1; e++) {
    int s = csr[e];
    float cf = di * dinv[s];
    unsigned u = h[(size_t)s * 64 + lane];
    acc0 += cf * __builtin_amdgcn_cvt_f32_fp8(u, 0);
    acc1 += cf * __builtin_amdgcn_cvt_f32_fp8(u, 1);
  }
  if (write16) {
    out16[(size_t)node * 64 + lane] =
        (unsigned)f2b(fmaxf(acc0, 0.f)) | ((unsigned)f2b(fmaxf(acc1, 0.f)) << 16);
  } else {
    ((float2*)out32)[(size_t)node * 64 + lane] = make_float2(acc0, acc1);
  }
}

extern "C" void kernel_launch(void* const* d_in, const int* in_sizes, int n_in,
                              void* d_out, int out_size, void* d_ws, size_t ws_size,
                              hipStream_t stream) {
  const float* x = (const float*)d_in[0];
  const int* src = (const int*)d_in[1];
  const int* dst = (const int*)d_in[2];
  const float* W1 = (const float*)d_in[3];
  const float* b1 = (const float*)d_in[4];
  const float* W2 = (const float*)d_in[5];
  const float* b2 = (const float*)d_in[6];
  int N = in_sizes[0] / H;
  int E = in_sizes[1];
  float* out = (float*)d_out;

  char* p = (char*)d_ws;
  auto alloc = [&](size_t bytes) {
    char* q = p;
    p += (bytes + 255) & ~(size_t)255;
    return q;
  };
  int* cnt = (int*)alloc((size_t)N * 4);
  int* roff = (int*)alloc((size_t)(N + 1) * 4);
  float* dinv = (float*)alloc((size_t)N * 4);
  int* csr = (int*)alloc((size_t)E * 4);
  unsigned int* xb = (unsigned int*)alloc((size_t)N * H * 2);         // bf16 x
  unsigned char* htmp = (unsigned char*)alloc((size_t)N * H);         // fp8 h = f@W
  unsigned int* fbuf = (unsigned int*)alloc((size_t)N * H * 2);       // bf16 relu(y)
  unsigned short* Wt1 = (unsigned short*)alloc(128 * 128 * 2);
  unsigned short* Wt2 = (unsigned short*)alloc(128 * 128 * 2);
  int* bsum = (int*)alloc(1024 * 4);
  int* boff = (int*)alloc(1024 * 4);
  int* rank = (int*)alloc((size_t)E * 4);   // live only deg->fill

  int nb = (N + SCAN_BLK - 1) / SCAN_BLK;  // 98 for N=100000

  hipMemsetAsync(cnt, 0, (size_t)N * 4, stream);
  k_deg<<<(E + 255) / 256, 256, 0, stream>>>(dst, cnt, rank, E);
  k_scan1<<<nb, 256, 0, stream>>>(cnt, bsum, N);
  k_scan2<<<1, 1024, 0, stream>>>(bsum, boff, roff, nb, N);
  k_scan3<<<nb, 256, 0, stream>>>(cnt, boff, roff, dinv, N);
  k_fill<<<(E + 255) / 256, 256, 0, stream>>>(src, dst, rank, roff, csr, E);
  k_prep_w<<<2, 256, 0, stream>>>(W1, W2, Wt1, Wt2);
  k_prep_xb<<<(N * (H / 2) + 255) / 256, 256, 0, stream>>>(x, xb, N * (H / 2));

  int gb = (N + 63) / 64;
  int ab = (N + 3) / 4;

  // layer 1: h = xb @ W1 ; y1 = agg(h) + b1 + xb ; relu -> fbuf
  k_gemm<<<gb, 256, 0, stream>>>(xb, Wt1, htmp, N);
  k_agg<<<ab, 256, 0, stream>>>((const unsigned short*)htmp, csr, roff, dinv, b1, xb,
                                nullptr, fbuf, N, 1);
  // layer 2
  k_gemm<<<gb, 256, 0, stream>>>(fbuf, Wt2, htmp, N);
  k_agg<<<ab, 256, 0, stream>>>((const unsigned short*)htmp, csr, roff, dinv, b2, xb,
                                nullptr, fbuf, N, 1);
  // layer 3 -> fp32 out
  k_gemm<<<gb, 256, 0, stream>>>(fbuf, Wt2, htmp, N);
  k_agg<<<ab, 256, 0, stream>>>((const unsigned short*)htmp, csr, roff, dinv, b2, xb,
                                out, nullptr, N, 0);
}